// Round 1
// 521.557 us; speedup vs baseline: 1.0951x; 1.0951x over previous
//
#include <hip/hip_runtime.h>

// ---------------------------------------------------------------------------
// Fused attention: Q/K/V = x@W^T + b ; RoPE(Q,K) ; softmax(QK^T/sqrt(D)) @ V
// B=32 S=1024 D=768.  fp16 MFMA (16x16x32), fp32 accumulate.
// R4: 256x256 tile, 512 thr / 8 waves (2Mx4N), BK=64, double-buffered LDS
//     (128 KiB), counted-vmcnt pipeline (T3+T4): loads for tile t+2 stay in
//     flight across barriers; raw s_barrier + manual waitcnts; setprio around
//     MFMA clusters (T5); XOR-swizzled LDS kept (0 bank conflicts measured);
//     XCD-chunked grid decode for L2 panel reuse.
// Safety-by-construction: stage targets only regions all waves have fully
//     ds_read this K-tile (lgkmcnt(0)+barrier precedes every stage); reads of
//     the other buffer are guarded by vmcnt(8)+barrier (8 = loads of tile
//     t+2, so tile t+1's 8 oldest have landed).
// ---------------------------------------------------------------------------

typedef __attribute__((ext_vector_type(8))) _Float16 f16x8;
typedef __attribute__((ext_vector_type(4))) float    f32x4;

__device__ __forceinline__ unsigned short f2h(float f) {
    _Float16 h = (_Float16)f;
    return __builtin_bit_cast(unsigned short, h);
}
__device__ __forceinline__ float h2f(unsigned short u) {
    return (float)__builtin_bit_cast(_Float16, u);
}

__device__ __forceinline__ void async_ld16(const void* g, void* l) {
    __builtin_amdgcn_global_load_lds(
        (const __attribute__((address_space(1))) void*)g,
        (__attribute__((address_space(3))) void*)l, 16, 0, 0);
}

// MODE 0: QK proj: A=x[32768x768], B=Wqk[1536x768]; bias+RoPE; Q*=scale. grid 768
// MODE 1: V^T:    A=Wv[768x768],  B=x[32768x768]; bias[row]; out [b][d][s]. grid 384
// MODE 2: scores: A=Q[b], B=K[b], fp16 out [q][k]. grid 512
// MODE 3: PV:     A=P[b], B=Vt[b], fp32 out [q][d]. grid 384
template<int MODE, int KDIM, int LDA, int LDB>
__global__ __launch_bounds__(512, 2)
void gemm_bt(const unsigned short* __restrict__ A,
             const unsigned short* __restrict__ B,
             void* __restrict__ C0, void* __restrict__ C1,
             const float* __restrict__ bias0,
             const float* __restrict__ bias1,
             float scale)
{
    // [2 buffers][256 rows][64 halfs]; 16B-chunk p of row r holds logical
    // k-chunk p^(r&7): staging swizzles the GLOBAL source, LDS stays linear.
    __shared__ __align__(16) unsigned short sA[2][256 * 64];
    __shared__ __align__(16) unsigned short sB[2][256 * 64];

    const int tid  = threadIdx.x;
    const int lane = tid & 63;
    const int wave = tid >> 6;          // 0..7
    const int wm   = wave >> 2;         // 0..1  (M half)
    const int wn   = wave & 3;          // 0..3  (N quarter)
    const int wrow = wm * 128;
    const int wcol = wn * 64;
    const int quad = lane >> 4;
    const int l15  = lane & 15;

    // --- XCD-chunked decode: blockIdx%8 ~ XCD; give each XCD a contiguous
    //     panel-sharing run so the shared operand stays in its 4 MiB L2. ---
    const int xcd = blockIdx.x & 7;
    const int bi  = blockIdx.x >> 3;
    int m0, n0, z = 0;
    if constexpr (MODE == 0) {          // 128 m-tiles x 6 n-tiles
        m0 = (xcd * 16 + bi / 6) * 256;  n0 = (bi % 6) * 256;
    } else if constexpr (MODE == 1) {   // 3 m-tiles x 128 n-tiles
        n0 = (xcd * 16 + bi / 3) * 256;  m0 = (bi % 3) * 256;
    } else if constexpr (MODE == 2) {   // 32 z x (4x4 tiles)
        z = xcd * 4 + bi / 16; const int t = bi % 16;
        m0 = (t >> 2) * 256; n0 = (t & 3) * 256;
    } else {                            // 32 z x (4x3 tiles)
        z = xcd * 4 + bi / 12; const int t = bi % 12;
        m0 = (t / 3) * 256;  n0 = (t % 3) * 256;
    }

    const unsigned short* Ab = A;
    const unsigned short* Bb = B;
    if constexpr (MODE == 2) { Ab += (size_t)z * 786432;  Bb += (size_t)z * 786432; }
    if constexpr (MODE == 3) { Ab += (size_t)z * 1048576; Bb += (size_t)z * 786432; }

    // Staging: each call = 1 global_load_lds covering 64 rows x 8 chunks.
    const int srow = tid >> 3;                       // 0..63
    const int sk   = ((tid & 7) ^ (srow & 7)) * 8;   // swizzled logical k-chunk
    const int sdst = (tid & 7) * 8;

    auto stgA = [&](int buf, int r0, int kt) {
        async_ld16(Ab + (size_t)(m0 + r0 + srow) * LDA + kt + sk,
                   &sA[buf][(r0 + srow) * 64 + sdst]);
    };
    auto stgB = [&](int buf, int r0, int kt) {
        async_ld16(Bb + (size_t)(n0 + r0 + srow) * LDB + kt + sk,
                   &sB[buf][(r0 + srow) * 64 + sdst]);
    };

    f32x4 acc[8][4] = {};

    constexpr int NT = KDIM / 64;

    // Prologue: tiles 0 and 1 (8 loads each); wait for tile 0 only.
    stgA(0, 0, 0); stgA(0, 128, 0); stgB(0, 0, 0); stgB(0, 64, 0);
    stgA(0, 64, 0); stgA(0, 192, 0); stgB(0, 128, 0); stgB(0, 192, 0);
    stgA(1, 0, 64); stgA(1, 128, 64); stgB(1, 0, 64); stgB(1, 64, 64);
    stgA(1, 64, 64); stgA(1, 192, 64); stgB(1, 128, 64); stgB(1, 192, 64);
    asm volatile("s_waitcnt vmcnt(8)" ::: "memory");
    __builtin_amdgcn_s_barrier();

    int p = 0;
    #pragma unroll 2
    for (int t = 0; t < NT; ++t, p ^= 1) {
        const int  kt2  = (t + 2) * 64;
        const bool pref = (t + 2) < NT;
        const unsigned short* sAp = sA[p];
        const unsigned short* sBp = sB[p];

        // ---- Phase A: frags for M-half 0 (all B cols, both k-halves) ----
        f16x8 bfr[4][2], af[4][2];
        #pragma unroll
        for (int ni = 0; ni < 4; ++ni) {
            const int r = wcol + ni * 16 + l15;
            const int x = r & 7;
            bfr[ni][0] = *(const f16x8*)&sBp[r * 64 + ((quad       ^ x) << 3)];
            bfr[ni][1] = *(const f16x8*)&sBp[r * 64 + (((4 + quad) ^ x) << 3)];
        }
        #pragma unroll
        for (int mi = 0; mi < 4; ++mi) {
            const int r = wrow + mi * 16 + l15;
            const int x = r & 7;
            af[mi][0] = *(const f16x8*)&sAp[r * 64 + ((quad       ^ x) << 3)];
            af[mi][1] = *(const f16x8*)&sAp[r * 64 + (((4 + quad) ^ x) << 3)];
        }
        asm volatile("s_waitcnt lgkmcnt(0)" ::: "memory");
        __builtin_amdgcn_s_barrier();
        // A rows {0-63,128-191} and all B rows consumed -> stage tile t+2.
        if (pref) { stgA(p, 0, kt2); stgA(p, 128, kt2);
                    stgB(p, 0, kt2); stgB(p, 64, kt2); }
        __builtin_amdgcn_s_setprio(1);
        #pragma unroll
        for (int mi = 0; mi < 4; ++mi)
            #pragma unroll
            for (int ni = 0; ni < 4; ++ni) {
                acc[mi][ni] = __builtin_amdgcn_mfma_f32_16x16x32_f16(
                    af[mi][0], bfr[ni][0], acc[mi][ni], 0, 0, 0);
                acc[mi][ni] = __builtin_amdgcn_mfma_f32_16x16x32_f16(
                    af[mi][1], bfr[ni][1], acc[mi][ni], 0, 0, 0);
            }
        __builtin_amdgcn_s_setprio(0);

        // ---- Phase B: frags for M-half 1 (B frags reused from registers) ----
        #pragma unroll
        for (int mi = 0; mi < 4; ++mi) {
            const int r = wrow + 64 + mi * 16 + l15;
            const int x = r & 7;
            af[mi][0] = *(const f16x8*)&sAp[r * 64 + ((quad       ^ x) << 3)];
            af[mi][1] = *(const f16x8*)&sAp[r * 64 + (((4 + quad) ^ x) << 3)];
        }
        asm volatile("s_waitcnt lgkmcnt(0)" ::: "memory");
        __builtin_amdgcn_s_barrier();
        if (pref) { stgA(p, 64, kt2); stgA(p, 192, kt2);
                    stgB(p, 128, kt2); stgB(p, 192, kt2); }
        __builtin_amdgcn_s_setprio(1);
        #pragma unroll
        for (int mi = 0; mi < 4; ++mi)
            #pragma unroll
            for (int ni = 0; ni < 4; ++ni) {
                acc[4 + mi][ni] = __builtin_amdgcn_mfma_f32_16x16x32_f16(
                    af[mi][0], bfr[ni][0], acc[4 + mi][ni], 0, 0, 0);
                acc[4 + mi][ni] = __builtin_amdgcn_mfma_f32_16x16x32_f16(
                    af[mi][1], bfr[ni][1], acc[4 + mi][ni], 0, 0, 0);
            }
        __builtin_amdgcn_s_setprio(0);

        // Counted drain: tile t+2's 8 loads stay in flight across barrier;
        // the 8 oldest (tile t+1) are guaranteed landed for next iteration.
        if (pref) asm volatile("s_waitcnt vmcnt(8)" ::: "memory");
        else      asm volatile("s_waitcnt vmcnt(0)" ::: "memory");
        __builtin_amdgcn_s_barrier();
    }

    // Epilogue. C/D layout: col = lane&15, row = quad*4 + reg  [m89-verified]
    const bool evenlane = (l15 & 1) == 0;

    float invf[4];
    if constexpr (MODE == 0) {
        #pragma unroll
        for (int ni = 0; ni < 4; ++ni) {
            int col = n0 + wcol + ni * 16 + l15;
            if (col >= 768) col -= 768;
            // inv_freq[i] = 2^(-i * 2*log2(10000)/768)
            invf[ni] = exp2f((float)(col >> 1) * -0.03460341765507773f);
        }
    }

    #pragma unroll
    for (int mi = 0; mi < 8; ++mi) {
        const int rowoff = (mi & 3) * 16 + (mi >> 2) * 64;
        #pragma unroll
        for (int ni = 0; ni < 4; ++ni) {
            #pragma unroll
            for (int reg = 0; reg < 4; ++reg) {
                const int grow = m0 + wrow + rowoff + quad * 4 + reg;
                const int gcol = n0 + wcol + ni * 16 + l15;
                float v = acc[mi][ni][reg];
                if constexpr (MODE == 0) {
                    const bool isQ = gcol < 768;          // block-uniform
                    const int  col = isQ ? gcol : gcol - 768;
                    v += isQ ? bias0[col] : bias1[col];
                    const float other = __shfl_xor(v, 1); // RoPE partner column
                    const int   s     = grow & 1023;
                    const float ang   = (float)s * invf[ni];
                    float sn, cs;
                    __sincosf(ang, &sn, &cs);
                    float r = (col & 1) ? fmaf(other, sn, v * cs)
                                        : fmaf(v, cs, -(other * sn));
                    if (isQ) r *= scale;
                    const unsigned short h = f2h(r);
                    const unsigned int packed =
                        (unsigned int)h | (__shfl_xor((unsigned int)h, 1) << 16);
                    if (evenlane) {
                        unsigned short* dst = (unsigned short*)(isQ ? C0 : C1);
                        *(unsigned int*)(dst + (size_t)grow * 768 + col) = packed;
                    }
                } else if constexpr (MODE == 1) {
                    v += bias0[grow];  // output feature = row (d)
                    const unsigned short h = f2h(v);
                    const unsigned int packed =
                        (unsigned int)h | (__shfl_xor((unsigned int)h, 1) << 16);
                    if (evenlane) {
                        const int b = gcol >> 10, s = gcol & 1023;
                        *(unsigned int*)((unsigned short*)C0 + (size_t)b * (768 * 1024)
                                         + (size_t)grow * 1024 + s) = packed;
                    }
                } else if constexpr (MODE == 2) {
                    const unsigned short h = f2h(v);
                    const unsigned int packed =
                        (unsigned int)h | (__shfl_xor((unsigned int)h, 1) << 16);
                    if (evenlane) {
                        *(unsigned int*)((unsigned short*)C0 + (size_t)z * 1048576
                                         + (size_t)grow * 1024 + gcol) = packed;
                    }
                } else {
                    const float vo = __shfl_xor(v, 1);
                    if (evenlane) {
                        float2 pk; pk.x = v; pk.y = vo;
                        *(float2*)(((float*)C0) + (size_t)z * 786432
                                   + (size_t)grow * 768 + gcol) = pk;
                    }
                }
            }
        }
    }
}

__global__ __launch_bounds__(256)
void softmax_rows(const unsigned short* __restrict__ S, unsigned short* __restrict__ P)
{
    const int row = blockIdx.x;           // 32*1024 rows
    const int tid = threadIdx.x;
    const ushort4 u = ((const ushort4*)(S + (size_t)row * 1024))[tid];
    const float v0 = h2f(u.x), v1 = h2f(u.y), v2 = h2f(u.z), v3 = h2f(u.w);

    float m = fmaxf(fmaxf(v0, v1), fmaxf(v2, v3));
    #pragma unroll
    for (int o = 1; o < 64; o <<= 1) m = fmaxf(m, __shfl_xor(m, o));
    __shared__ float redm[4];
    __shared__ float reds[4];
    const int wave = tid >> 6, lane = tid & 63;
    if (lane == 0) redm[wave] = m;
    __syncthreads();
    m = fmaxf(fmaxf(redm[0], redm[1]), fmaxf(redm[2], redm[3]));

    const float e0 = __expf(v0 - m), e1 = __expf(v1 - m);
    const float e2 = __expf(v2 - m), e3 = __expf(v3 - m);
    float sum = e0 + e1 + e2 + e3;
    #pragma unroll
    for (int o = 1; o < 64; o <<= 1) sum += __shfl_xor(sum, o);
    if (lane == 0) reds[wave] = sum;
    __syncthreads();
    sum = reds[0] + reds[1] + reds[2] + reds[3];
    const float inv = 1.0f / sum;

    ushort4 o4;
    o4.x = f2h(e0 * inv); o4.y = f2h(e1 * inv);
    o4.z = f2h(e2 * inv); o4.w = f2h(e3 * inv);
    ((ushort4*)(P + (size_t)row * 1024))[tid] = o4;
}

__global__ void cvt_f32_f16(const float4* __restrict__ in,
                            ushort4* __restrict__ out, int n4)
{
    int i = blockIdx.x * 256 + threadIdx.x;
    const int stride = gridDim.x * 256;
    for (; i < n4; i += stride) {
        const float4 v = in[i];
        ushort4 o;
        o.x = f2h(v.x); o.y = f2h(v.y); o.z = f2h(v.z); o.w = f2h(v.w);
        out[i] = o;
    }
}

extern "C" void kernel_launch(void* const* d_in, const int* in_sizes, int n_in,
                              void* d_out, int out_size, void* d_ws, size_t ws_size,
                              hipStream_t stream)
{
    const float* x  = (const float*)d_in[0];
    const float* Wq = (const float*)d_in[1];
    const float* bq = (const float*)d_in[2];
    const float* Wk = (const float*)d_in[3];
    const float* bk = (const float*)d_in[4];
    const float* Wv = (const float*)d_in[5];
    const float* bv = (const float*)d_in[6];
    float* out = (float*)d_out;

    // Workspace layout (bytes). High-water: ~272 MB.
    char* ws = (char*)d_ws;
    unsigned short* xh  = (unsigned short*)(ws + 0);          // 48 MB fp16 x
    unsigned short* wqk = (unsigned short*)(ws + 50331648);   // Wq||Wk [1536][768]
    unsigned short* wvh = (unsigned short*)(ws + 52690944);
    unsigned short* Qh  = (unsigned short*)(ws + 53870592);   // 48 MB
    unsigned short* Kh  = (unsigned short*)(ws + 104202240);  // 48 MB
    unsigned short* Vt  = (unsigned short*)(ws + 154533888);  // 48 MB  [b][d][s]
    unsigned short* Sc  = (unsigned short*)(ws + 204865536);  // 64 MB fp16 scores
    unsigned short* Ph  = (unsigned short*)(ws + 0);          // 64 MB (x/W dead)

    // 1) fp32 -> fp16 conversions
    cvt_f32_f16<<<4096, 256, 0, stream>>>((const float4*)x,  (ushort4*)xh, 25165824 / 4);
    cvt_f32_f16<<<576,  256, 0, stream>>>((const float4*)Wq, (ushort4*)wqk, 589824 / 4);
    cvt_f32_f16<<<576,  256, 0, stream>>>((const float4*)Wk, (ushort4*)(wqk + 589824), 589824 / 4);
    cvt_f32_f16<<<576,  256, 0, stream>>>((const float4*)Wv, (ushort4*)wvh, 589824 / 4);

    const float qscale = 0.03608439182435161f;  // 1/sqrt(768), folded into Q

    // 2) Q,K = rope(x@Wqk^T + b) (Q scaled); fused over concatenated Wqk
    gemm_bt<0, 768, 768, 768><<<768, 512, 0, stream>>>(
        xh, wqk, Qh, Kh, bq, bk, qscale);
    // 3) V^T[b][d][s] via swapped operands
    gemm_bt<1, 768, 768, 768><<<384, 512, 0, stream>>>(
        wvh, xh, Vt, nullptr, bv, nullptr, 1.0f);
    // 4) scores[b] = Q[b] @ K[b]^T  (scale already in Q), fp16 out
    gemm_bt<2, 768, 768, 768><<<512, 512, 0, stream>>>(
        Qh, Kh, Sc, nullptr, nullptr, nullptr, 1.0f);
    // 5) P = softmax(scores) as fp16
    softmax_rows<<<32768, 256, 0, stream>>>(Sc, Ph);
    // 6) out[b] = P[b] @ V[b] == gemm_bt(P, V^T)
    gemm_bt<3, 1024, 1024, 1024><<<384, 512, 0, stream>>>(
        Ph, Vt, out, nullptr, nullptr, nullptr, 1.0f);
}